// Round 1
// baseline (400.322 us; speedup 1.0000x reference)
//
#include <hip/hip_runtime.h>
#include <stdint.h>

// DISCO equidistant conv2d: depthwise 5x5, stride 2, zero pad 2.
// x: (4,16,1024,1024) f32, weight: (16,1,3) f32, bias: (16,) f32, psi: (3,5,5) f32
// out: (4,16,512,512) f32
//
// out[b,o,i,j] = bias[o] + sum_{dy,dx} K[o,dy,dx] * X(b,o, 2i+dy-2, 2j+dx-2)
// K[o,dy,dx]  = QW * sum_k weight[o,k] * psi[k,dy,dx]

#define H_IN   1024
#define W_IN   1024
#define H_OUT  512
#define W_OUT  512
#define CCH    16
#define BATCH  4
#define NRB    3
#define PSIW   5
#define ROWS_OUT 4
#define ROWS_IN  (2 * ROWS_OUT + 3)   // 11 staged input rows per tile
#define PITCH    1032                 // floats per LDS row (1028 used + pad)
#define QW 3.814697265625e-06f        // 2*2/(1024*1024)

__global__ __launch_bounds__(256) void disco_conv_kernel(
    const float* __restrict__ x,
    const float* __restrict__ weight,
    const float* __restrict__ bias,
    const float* __restrict__ psi,
    float* __restrict__ out)
{
    // LDS layout: tile[rr][l], l = x_col + 4  (x_col in [-4..1027] conceptually;
    // valid x cols 0..1023 live at l=4..1027; zero halo at l=2,3 (cols -2,-1)
    // and l=1028 (col 1024); l=0,1,1029..1031 are don't-care).
    __shared__ __align__(16) float tile[ROWS_IN * PITCH];
    __shared__ float kbuf[32];

    const int t  = threadIdx.x;          // 0..255
    const int i0 = blockIdx.x * ROWS_OUT;
    const int o  = blockIdx.y;
    const int b  = blockIdx.z;

    const float* plane = x + (size_t)(b * CCH + o) * (H_IN * W_IN);

    // --- per-channel 5x5 kernel from basis coefficients (once per block) ---
    if (t < 25) {
        const int dy = t / 5, dx = t % 5;
        const float w0 = weight[o * NRB + 0];
        const float w1 = weight[o * NRB + 1];
        const float w2 = weight[o * NRB + 2];
        kbuf[t] = QW * (w0 * psi[(0 * PSIW + dy) * PSIW + dx] +
                        w1 * psi[(1 * PSIW + dy) * PSIW + dx] +
                        w2 * psi[(2 * PSIW + dy) * PSIW + dx]);
    }

    // --- stage 11 input rows (coalesced float4 loads -> aligned b128 LDS writes) ---
    const int y_base = 2 * i0 - 2;
    #pragma unroll
    for (int rr = 0; rr < ROWS_IN; ++rr) {
        const int y = y_base + rr;
        float4 v = make_float4(0.f, 0.f, 0.f, 0.f);
        if ((unsigned)y < (unsigned)H_IN) {
            v = *(const float4*)(plane + (size_t)y * W_IN + 4 * t);
        }
        *(float4*)&tile[rr * PITCH + 4 + 4 * t] = v;            // 16B-aligned
        if (t == 0) {                                           // left halo zeros
            tile[rr * PITCH + 2] = 0.f;
            tile[rr * PITCH + 3] = 0.f;
        }
        if (t == 1) {                                           // right halo zeros
            *(float4*)&tile[rr * PITCH + 1028] = make_float4(0.f, 0.f, 0.f, 0.f);
        }
    }
    __syncthreads();

    float K[25];
    #pragma unroll
    for (int n = 0; n < 25; ++n) K[n] = kbuf[n];   // LDS broadcast, conflict-free

    const float bo = bias[o];
    float acc[ROWS_OUT][2];
    #pragma unroll
    for (int ip = 0; ip < ROWS_OUT; ++ip) { acc[ip][0] = bo; acc[ip][1] = bo; }

    // --- compute: thread t handles output cols j0=2t, j1=2t+1 for 4 rows ---
    // f[n] = tile[rr][4t + n]  <->  x col = 4t + n - 4
    // j0 needs x cols 4t-2..4t+2 -> f[2..6];  j1 needs 4t..4t+4 -> f[4..8]
    #pragma unroll
    for (int rr = 0; rr < ROWS_IN; ++rr) {
        const float* row = &tile[rr * PITCH + 4 * t];
        const float4 va = *(const float4*)(row);        // f0..f3
        const float4 vb = *(const float4*)(row + 4);    // f4..f7
        const float2 vc = *(const float2*)(row + 8);    // f8,f9
        const float f[10] = { va.x, va.y, va.z, va.w,
                              vb.x, vb.y, vb.z, vb.w,
                              vc.x, vc.y };
        #pragma unroll
        for (int ip = 0; ip < ROWS_OUT; ++ip) {
            const int dy = rr - 2 * ip;
            if (dy >= 0 && dy < 5) {
                #pragma unroll
                for (int dx = 0; dx < 5; ++dx) {
                    const float kv = K[dy * 5 + dx];
                    acc[ip][0] += kv * f[2 + dx];
                    acc[ip][1] += kv * f[4 + dx];
                }
            }
        }
    }

    // --- coalesced float2 stores ---
    float* oplane = out + (size_t)(b * CCH + o) * (H_OUT * W_OUT);
    #pragma unroll
    for (int ip = 0; ip < ROWS_OUT; ++ip) {
        *(float2*)(oplane + (size_t)(i0 + ip) * W_OUT + 2 * t) =
            make_float2(acc[ip][0], acc[ip][1]);
    }
}

extern "C" void kernel_launch(void* const* d_in, const int* in_sizes, int n_in,
                              void* d_out, int out_size, void* d_ws, size_t ws_size,
                              hipStream_t stream) {
    const float* x      = (const float*)d_in[0];
    const float* weight = (const float*)d_in[1];
    const float* bias   = (const float*)d_in[2];
    const float* psi    = (const float*)d_in[3];
    float* out          = (float*)d_out;

    dim3 grid(H_OUT / ROWS_OUT, CCH, BATCH);   // (128, 16, 4) = 8192 blocks
    disco_conv_kernel<<<grid, 256, 0, stream>>>(x, weight, bias, psi, out);
}

// Round 3
// 381.402 us; speedup vs baseline: 1.0496x; 1.0496x over previous
//
#include <hip/hip_runtime.h>
#include <stdint.h>

// DISCO equidistant conv2d: depthwise 5x5, stride 2, zero pad 2.
// x: (4,16,1024,1024) f32, weight: (16,1,3) f32, bias: (16,) f32, psi: (3,5,5) f32
// out: (4,16,512,512) f32
//
// out[b,o,i,j] = bias[o] + sum_{dy,dx} K[o,dy,dx] * X(b,o, 2i+dy-2, 2j+dx-2)
// K[o,dy,dx]  = QW * sum_k weight[o,k] * psi[k,dy,dx]
//
// Tile: 4 out-rows x 256 out-cols per block -> 11 staged in-rows x 520 floats
// LDS = 22.9 KB -> 7 blocks/CU (28 waves/CU) for latency hiding.

#define H_IN   1024
#define W_IN   1024
#define H_OUT  512
#define W_OUT  512
#define CCH    16
#define NRB    3
#define PSIW   5
#define ROWS_OUT 4
#define ROWS_IN  11                   // 2*ROWS_OUT + 3
#define COLS_OUT 256
#define LROW     520                  // floats per LDS row; l -> x col = x0 + l
#define CHUNKS_PER_ROW (LROW / 4)     // 130 float4 chunks
#define NCHUNK   (ROWS_IN * CHUNKS_PER_ROW)   // 1430
#define QW 3.814697265625e-06f        // 2*2/(1024*1024)

typedef float vf2 __attribute__((ext_vector_type(2)));   // native vector for nontemporal store

__global__ __launch_bounds__(256) void disco_conv_kernel(
    const float* __restrict__ x,
    const float* __restrict__ weight,
    const float* __restrict__ bias,
    const float* __restrict__ psi,
    float* __restrict__ out)
{
    __shared__ __align__(16) float tile[ROWS_IN * LROW];   // 22880 B
    __shared__ float kbuf[32];

    const int t  = threadIdx.x;          // 0..255
    const int bx = blockIdx.x;           // 256 = 2 col-tiles * 128 row-tiles
    const int ct = bx & 1;
    const int rt = bx >> 1;
    const int o  = blockIdx.y;
    const int b  = blockIdx.z;

    const int i0 = rt * ROWS_OUT;        // first output row
    const int j0 = ct * COLS_OUT;        // first output col
    const int x0 = 2 * j0 - 4;           // x col of LDS l=0 (16B-aligned chunks)
    const int y0 = 2 * i0 - 2;           // x row of LDS rr=0

    const float* plane = x + (size_t)(b * CCH + o) * (H_IN * W_IN);

    // --- per-channel 5x5 kernel from basis coefficients (once per block) ---
    if (t < 25) {
        const int dy = t / 5, dx = t % 5;
        const float w0 = weight[o * NRB + 0];
        const float w1 = weight[o * NRB + 1];
        const float w2 = weight[o * NRB + 2];
        kbuf[t] = QW * (w0 * psi[(0 * PSIW + dy) * PSIW + dx] +
                        w1 * psi[(1 * PSIW + dy) * PSIW + dx] +
                        w2 * psi[(2 * PSIW + dy) * PSIW + dx]);
    }

    // --- stage 11 rows x 520 cols (coalesced float4, zero halo via predication) ---
    #pragma unroll
    for (int it = 0; it < 6; ++it) {
        const int q = t + it * 256;
        if (q < NCHUNK) {
            const int rr = q / CHUNKS_PER_ROW;        // magic-mul div
            const int m  = q - rr * CHUNKS_PER_ROW;
            const int y  = y0 + rr;
            const int xc = x0 + 4 * m;                // chunk never partially valid
            float4 v = make_float4(0.f, 0.f, 0.f, 0.f);
            if ((unsigned)y < (unsigned)H_IN && (unsigned)xc <= (unsigned)(W_IN - 4)) {
                v = *(const float4*)(plane + (size_t)y * W_IN + xc);
            }
            *(float4*)&tile[rr * LROW + 4 * m] = v;   // 16B-aligned, conflict-free
        }
    }
    __syncthreads();

    float K[25];
    #pragma unroll
    for (int n = 0; n < 25; ++n) K[n] = kbuf[n];      // broadcast reads

    // thread t -> out cols j0 + {2c, 2c+1}, out rows i0 + 2*rho + {0,1}
    const int c   = t & 127;
    const int rho = t >> 7;
    const float bo = bias[o];
    float a00 = bo, a01 = bo;    // row s=0, cols 0/1
    float a10 = bo, a11 = bo;    // row s=1, cols 0/1

    // x row rr = 4*rho + 2*s + dy ; local l window = 4c + 2 .. 4c + 8
    const float* base = &tile[(4 * rho) * LROW + 4 * c];
    #pragma unroll
    for (int rl = 0; rl < 7; ++rl) {
        const float* row = base + rl * LROW;
        const float4 va = *(const float4*)(row);       // f0..f3 (16B aligned)
        const float4 vb = *(const float4*)(row + 4);   // f4..f7
        const float2 vc = *(const float2*)(row + 8);   // f8,f9
        const float f[10] = { va.x, va.y, va.z, va.w,
                              vb.x, vb.y, vb.z, vb.w,
                              vc.x, vc.y };
        if (rl < 5) {                                  // s=0, dy=rl
            #pragma unroll
            for (int dx = 0; dx < 5; ++dx) {
                const float kv = K[rl * 5 + dx];
                a00 += kv * f[2 + dx];
                a01 += kv * f[4 + dx];
            }
        }
        if (rl >= 2) {                                 // s=1, dy=rl-2
            #pragma unroll
            for (int dx = 0; dx < 5; ++dx) {
                const float kv = K[(rl - 2) * 5 + dx];
                a10 += kv * f[2 + dx];
                a11 += kv * f[4 + dx];
            }
        }
    }

    // --- coalesced nontemporal float2 stores (don't pollute L2/L3) ---
    float* oplane = out + (size_t)(b * CCH + o) * (H_OUT * W_OUT);
    const size_t o0 = (size_t)(i0 + 2 * rho) * W_OUT + j0 + 2 * c;
    vf2 s0; s0.x = a00; s0.y = a01;
    vf2 s1; s1.x = a10; s1.y = a11;
    __builtin_nontemporal_store(s0, (vf2*)(oplane + o0));
    __builtin_nontemporal_store(s1, (vf2*)(oplane + o0 + W_OUT));
}

extern "C" void kernel_launch(void* const* d_in, const int* in_sizes, int n_in,
                              void* d_out, int out_size, void* d_ws, size_t ws_size,
                              hipStream_t stream) {
    const float* x      = (const float*)d_in[0];
    const float* weight = (const float*)d_in[1];
    const float* bias   = (const float*)d_in[2];
    const float* psi    = (const float*)d_in[3];
    float* out          = (float*)d_out;

    dim3 grid(2 * (H_OUT / ROWS_OUT), CCH, 4);   // (256, 16, 4) = 16384 blocks
    disco_conv_kernel<<<grid, 256, 0, stream>>>(x, weight, bias, psi, out);
}